// Round 12
// baseline (110.045 us; speedup 1.0000x reference)
//
#include <hip/hip_runtime.h>

// Chamfer distance, B=8, N=M=8192, D=3, fp32 — MFMA with pre-packed frags.
// dist[i][j] = nx_i + ny_j - 2 x_i.y_j; out = mean(min_j) + mean(min_i).
//
// K=16 bf16-split packing (validated R8-R11, absmax ~0):
//   A row = [ah0 ah1 ah2 ah0 ah1 ah2 al0 al1 | al2 nxh nxl 1 1 0 0 0]
//   B col = [yh0 yh1 yh2 yl0 yl1 yl2 yh0 yh1 | yh2 1 1 nyh nyl 0 0 0]
//
// R12: R9-R11 all ~44us regardless of tiling => the ~30us over the 13.8us
// MFMA floor is shared serialization: in-loop frag BUILD (global-load stall
// + ~50 VALU/thread/chunk), un-prefetched ds_reads, and acc serialization
// (VGPR=60). Fixes:
//  - pre_k packs A/B-role frags for x and y into d_ws; main staging is a
//    plain coalesced uint4 copy (zero build VALU in the hot loop)
//  - split-phase dbuf: chunk+1 global loads issued BEFORE compute (hidden
//    under ~8k cyc of MFMA), ds_writes after compute
//  - explicit B-tile register prefetch + 2 independent acc-pairs (~110 VGPR
//    fits 128-cap at launch_bounds(512,4))

#define B_ 8
#define N_ 8192
#define PTS (B_ * N_)        // 65536 per set
#define TPB 512

typedef short bf16x8 __attribute__((ext_vector_type(8)));
typedef float f32x16 __attribute__((ext_vector_type(16)));

__device__ __forceinline__ unsigned b16(float f) {   // fp32 -> bf16 bits (RNE)
  unsigned u = __float_as_uint(f);
  return (u + 0x7FFFu + ((u >> 16) & 1u)) >> 16;
}
__device__ __forceinline__ float bf(unsigned h) { return __uint_as_float(h << 16); }

// ---- pre: pack A-role and B-role fragments for both point sets ----
__global__ __launch_bounds__(256) void chamfer_pre_k(
    const float* __restrict__ x, const float* __restrict__ y,
    uint4* __restrict__ afX, uint4* __restrict__ bfX,
    uint4* __restrict__ afY, uint4* __restrict__ bfY,
    float* __restrict__ out) {
  int p = blockIdx.x * 256 + threadIdx.x;   // 0..PTS-1
  if (p == 0) out[0] = 0.0f;
  const unsigned one = 0x3F80u;
  int tile = p >> 5, m = p & 31;
  int i0 = tile * 64 + m, i1 = tile * 64 + 32 + m;

#pragma unroll
  for (int s = 0; s < 2; ++s) {
    const float* src = s ? y : x;
    uint4* af = s ? afY : afX;
    uint4* bf_ = s ? bfY : bfX;
    float v0 = src[3 * p], v1 = src[3 * p + 1], v2 = src[3 * p + 2];
    float nv = fmaf(v0, v0, fmaf(v1, v1, v2 * v2));
    unsigned nh = b16(nv), nl = b16(nv - bf(nh));
    // A-role: -2v split hi/lo
    float a0 = -2.0f * v0, a1 = -2.0f * v1, a2 = -2.0f * v2;
    unsigned ah0 = b16(a0), ah1 = b16(a1), ah2 = b16(a2);
    unsigned al0 = b16(a0 - bf(ah0)), al1 = b16(a1 - bf(ah1)), al2 = b16(a2 - bf(ah2));
    af[i0] = make_uint4(ah0 | (ah1 << 16), ah2 | (ah0 << 16),
                        ah1 | (ah2 << 16), al0 | (al1 << 16));
    af[i1] = make_uint4(al2 | (nh << 16), nl | (one << 16), one, 0u);
    // B-role: raw v split hi/lo
    unsigned yh0 = b16(v0), yh1 = b16(v1), yh2 = b16(v2);
    unsigned yl0 = b16(v0 - bf(yh0)), yl1 = b16(v1 - bf(yh1)), yl2 = b16(v2 - bf(yh2));
    bf_[i0] = make_uint4(yh0 | (yh1 << 16), yh2 | (yl0 << 16),
                         yl1 | (yl2 << 16), yh0 | (yh1 << 16));
    bf_[i1] = make_uint4(yh2 | (one << 16), one | (nh << 16), nl, 0u);
  }
}

__global__ __launch_bounds__(TPB, 4) void chamfer_main_k(
    const uint4* __restrict__ afX, const uint4* __restrict__ bfX,
    const uint4* __restrict__ afY, const uint4* __restrict__ bfY,
    float* __restrict__ gpart) {
  __shared__ uint4 ldsFrag[2][32 * 64];   // 2 x 32 KB double buffer

  int t = threadIdx.x, lane = t & 63, w = t >> 6;   // 8 waves
  int b = blockIdx.x;                    // 512 blocks
  int g = b >> 1;                        // row-group 0..255 (512 rows each)
  int hf = b & 1;                        // candidate half (4096 cands)
  int dir = g >> 7;                      // 0: rows=x scan y; 1: rows=y scan x
  int gg = g & 127;
  int batch = gg >> 4;
  int seg = gg & 15;                     // 512-row segment within batch
  const uint4* __restrict__ arow = dir ? afY : afX;
  const uint4* __restrict__ bcand = dir ? bfX : bfY;

  // ---- A-frags: 2 row-tiles (64 rows) per wave, direct load ----
  int tb = batch * 256 + seg * 16 + w * 2;          // row-tile index
  bf16x8 A0 = __builtin_bit_cast(bf16x8, arow[tb * 64 + lane]);
  bf16x8 A1 = __builtin_bit_cast(bf16x8, arow[(tb + 1) * 64 + lane]);

  f32x16 z = {0.f,0.f,0.f,0.f,0.f,0.f,0.f,0.f,0.f,0.f,0.f,0.f,0.f,0.f,0.f,0.f};
  f32x16 rm0, rm1;
#pragma unroll
  for (int r = 0; r < 16; ++r) { rm0[r] = 1e30f; rm1[r] = 1e30f; }

  // candidate chunks: 4 x 1024 cands = 4 x 2048 uint4 (32 KB)
  const uint4* __restrict__ cb = bcand + (batch * 256 + hf * 128) * 64;
  uint4 stg[4];
#pragma unroll
  for (int k = 0; k < 4; ++k) stg[k] = cb[t + k * TPB];     // chunk 0 loads
#pragma unroll
  for (int k = 0; k < 4; ++k) ldsFrag[0][t + k * TPB] = stg[k];
  __syncthreads();

  for (int ch = 0; ch < 4; ++ch) {
    const uint4* cur = ldsFrag[ch & 1];
    if (ch < 3) {                        // issue next chunk's global loads NOW
      const uint4* nxt = cb + (ch + 1) * 2048;
#pragma unroll
      for (int k = 0; k < 4; ++k) stg[k] = nxt[t + k * TPB];
    }

    // explicit B-register prefetch pipeline over 16 iters (32 tiles)
    uint4 b0 = cur[lane], b1 = cur[64 + lane];
    for (int i = 0; i < 16; ++i) {
      uint4 nb0, nb1;
      if (i < 15) { nb0 = cur[(2 * i + 2) * 64 + lane]; nb1 = cur[(2 * i + 3) * 64 + lane]; }
      bf16x8 Bt0 = __builtin_bit_cast(bf16x8, b0);
      bf16x8 Bt1 = __builtin_bit_cast(bf16x8, b1);
      f32x16 acc0 = __builtin_amdgcn_mfma_f32_32x32x16_bf16(A0, Bt0, z, 0, 0, 0);
      f32x16 acc1 = __builtin_amdgcn_mfma_f32_32x32x16_bf16(A0, Bt1, z, 0, 0, 0);
      f32x16 acc2 = __builtin_amdgcn_mfma_f32_32x32x16_bf16(A1, Bt0, z, 0, 0, 0);
      f32x16 acc3 = __builtin_amdgcn_mfma_f32_32x32x16_bf16(A1, Bt1, z, 0, 0, 0);
#pragma unroll
      for (int r = 0; r < 16; ++r) {
        rm0[r] = fminf(fminf(rm0[r], acc0[r]), acc1[r]);   // v_min3_f32
        rm1[r] = fminf(fminf(rm1[r], acc2[r]), acc3[r]);   // v_min3_f32
      }
      b0 = nb0; b1 = nb1;
    }

    __syncthreads();                     // cur's readers done
    if (ch < 3) {
      uint4* nbuf = ldsFrag[(ch + 1) & 1];
#pragma unroll
      for (int k = 0; k < 4; ++k) nbuf[t + k * TPB] = stg[k];
      __syncthreads();                   // next buffer ready
    }
  }

  // ---- epilogue: fold 32 cols per half (butterfly), store row-mins ----
#pragma unroll
  for (int msk = 1; msk <= 16; msk <<= 1)
#pragma unroll
    for (int r = 0; r < 16; ++r) {
      rm0[r] = fminf(rm0[r], __shfl_xor(rm0[r], msk, 64));
      rm1[r] = fminf(rm1[r], __shfl_xor(rm1[r], msk, 64));
    }

  float* gp = gpart + b * 512;           // this block's row-min slab
  if ((lane & 31) == 0) {                // lanes 0 and 32 (h = lane>>5)
    int h = lane >> 5;
#pragma unroll
    for (int r = 0; r < 16; ++r) {
      int rr = (r & 3) + 8 * (r >> 2) + 4 * h;
      gp[w * 64 + rr] = rm0[r];
      gp[w * 64 + 32 + rr] = rm1[r];
    }
  }
}

// ---- final: min the two candidate-halves, sum everything ----
__global__ __launch_bounds__(256) void chamfer_final_k(
    const float* __restrict__ gpart, float* __restrict__ out) {
  int i = blockIdx.x * 256 + threadIdx.x;   // 32768 threads x 4 rows
  float s = 0.0f;
#pragma unroll
  for (int e = 0; e < 4; ++e) {
    int rowid = 4 * i + e;               // 0 .. 131071
    int g = rowid >> 9, r = rowid & 511;
    s += fminf(gpart[(2 * g) * 512 + r], gpart[(2 * g + 1) * 512 + r]);
  }
  for (int off = 32; off > 0; off >>= 1) s += __shfl_down(s, off, 64);
  __shared__ float red[4];
  int lane = threadIdx.x & 63, wv = threadIdx.x >> 6;
  if (lane == 0) red[wv] = s;
  __syncthreads();
  if (threadIdx.x == 0) {
    float tt = (red[0] + red[1]) + (red[2] + red[3]);
    atomicAdd(out, tt * (1.0f / (float)PTS));
  }
}

extern "C" void kernel_launch(void* const* d_in, const int* in_sizes, int n_in,
                              void* d_out, int out_size, void* d_ws, size_t ws_size,
                              hipStream_t stream) {
  const float* x = (const float*)d_in[0];
  const float* y = (const float*)d_in[1];
  float* out = (float*)d_out;
  uint4* afX = (uint4*)d_ws;                 // 2048 tiles * 64 uint4 = 2 MB
  uint4* bfX = afX + 2048 * 64;              // 2 MB
  uint4* afY = bfX + 2048 * 64;              // 2 MB
  uint4* bfY = afY + 2048 * 64;              // 2 MB
  float* gpart = (float*)(bfY + 2048 * 64);  // 1 MB

  hipMemsetAsync(out, 0, sizeof(float), stream);
  chamfer_pre_k<<<PTS / 256, 256, 0, stream>>>(x, y, afX, bfX, afY, bfY, out);
  chamfer_main_k<<<512, TPB, 0, stream>>>(afX, bfX, afY, bfY, gpart);
  chamfer_final_k<<<128, 256, 0, stream>>>(gpart, out);
}

// Round 13
// 101.235 us; speedup vs baseline: 1.0870x; 1.0870x over previous
//
#include <hip/hip_runtime.h>

// Chamfer distance, B=8, N=M=8192, D=3, fp32 — MFMA + async global->LDS DMA.
// dist[i][j] = nx_i + ny_j - 2 x_i.y_j; out = mean(min_j) + mean(min_i).
//
// K=16 bf16-split packing (validated R8-R12, absmax ~0):
//   A row = [ah0 ah1 ah2 ah0 ah1 ah2 al0 al1 | al2 nxh nxl 1 1 0 0 0]
//   B col = [yh0 yh1 yh2 yl0 yl1 yl2 yh0 yh1 | yh2 1 1 nyh nyl 0 0 0]
//
// R13: R9-R11's ~44us = pipes running serially; every wave stalled on
// vmcnt before compute (staging in program order), and R12's register
// prefetch spilled to scratch (WRITE_SIZE 71MB). Fix per guide §5 (m97):
// __builtin_amdgcn_global_load_lds width=16 — async DMA, zero VGPRs,
// issued for chunk ch+1 BEFORE computing chunk ch; the drain folds into
// the existing __syncthreads() (s_waitcnt vmcnt(0) before s_barrier).
// Frags pre-packed in d_ws (R12's pre_k). Inner loop stays R11's
// 2 ds_read + 4 MFMA + 32 min3 with no register pipeline -> no spill.

#define B_ 8
#define N_ 8192
#define PTS (B_ * N_)        // 65536 per set
#define TPB 512

typedef short bf16x8 __attribute__((ext_vector_type(8)));
typedef float f32x16 __attribute__((ext_vector_type(16)));
typedef __attribute__((address_space(1))) const unsigned char ga_t;
typedef __attribute__((address_space(3))) unsigned char la_t;

__device__ __forceinline__ unsigned b16(float f) {   // fp32 -> bf16 bits (RNE)
  unsigned u = __float_as_uint(f);
  return (u + 0x7FFFu + ((u >> 16) & 1u)) >> 16;
}
__device__ __forceinline__ float bf(unsigned h) { return __uint_as_float(h << 16); }

// ---- pre: pack A-role and B-role fragments for both point sets ----
__global__ __launch_bounds__(256) void chamfer_pre_k(
    const float* __restrict__ x, const float* __restrict__ y,
    uint4* __restrict__ afX, uint4* __restrict__ bfX,
    uint4* __restrict__ afY, uint4* __restrict__ bfY,
    float* __restrict__ out) {
  int p = blockIdx.x * 256 + threadIdx.x;   // 0..PTS-1
  if (p == 0) out[0] = 0.0f;
  const unsigned one = 0x3F80u;
  int tile = p >> 5, m = p & 31;
  int i0 = tile * 64 + m, i1 = tile * 64 + 32 + m;

#pragma unroll
  for (int s = 0; s < 2; ++s) {
    const float* src = s ? y : x;
    uint4* af = s ? afY : afX;
    uint4* bf_ = s ? bfY : bfX;
    float v0 = src[3 * p], v1 = src[3 * p + 1], v2 = src[3 * p + 2];
    float nv = fmaf(v0, v0, fmaf(v1, v1, v2 * v2));
    unsigned nh = b16(nv), nl = b16(nv - bf(nh));
    float a0 = -2.0f * v0, a1 = -2.0f * v1, a2 = -2.0f * v2;
    unsigned ah0 = b16(a0), ah1 = b16(a1), ah2 = b16(a2);
    unsigned al0 = b16(a0 - bf(ah0)), al1 = b16(a1 - bf(ah1)), al2 = b16(a2 - bf(ah2));
    af[i0] = make_uint4(ah0 | (ah1 << 16), ah2 | (ah0 << 16),
                        ah1 | (ah2 << 16), al0 | (al1 << 16));
    af[i1] = make_uint4(al2 | (nh << 16), nl | (one << 16), one, 0u);
    unsigned yh0 = b16(v0), yh1 = b16(v1), yh2 = b16(v2);
    unsigned yl0 = b16(v0 - bf(yh0)), yl1 = b16(v1 - bf(yh1)), yl2 = b16(v2 - bf(yh2));
    bf_[i0] = make_uint4(yh0 | (yh1 << 16), yh2 | (yl0 << 16),
                         yl1 | (yl2 << 16), yh0 | (yh1 << 16));
    bf_[i1] = make_uint4(yh2 | (one << 16), one | (nh << 16), nl, 0u);
  }
}

__global__ __launch_bounds__(TPB, 4) void chamfer_main_k(
    const uint4* __restrict__ afX, const uint4* __restrict__ bfX,
    const uint4* __restrict__ afY, const uint4* __restrict__ bfY,
    float* __restrict__ gpart) {
  __shared__ uint4 ldsFrag[2][32 * 64];   // 2 x 32 KB double buffer

  int t = threadIdx.x, lane = t & 63, w = t >> 6;   // 8 waves
  int b = blockIdx.x;                    // 512 blocks
  int g = b >> 1;                        // row-group 0..255 (512 rows each)
  int hf = b & 1;                        // candidate half (4096 cands)
  int dir = g >> 7;                      // 0: rows=x scan y; 1: rows=y scan x
  int gg = g & 127;
  int batch = gg >> 4;
  int seg = gg & 15;                     // 512-row segment within batch
  const uint4* __restrict__ arow = dir ? afY : afX;
  const uint4* __restrict__ bcand = dir ? bfX : bfY;

  // ---- A-frags: 2 row-tiles (64 rows) per wave, direct load ----
  int tb = batch * 256 + seg * 16 + w * 2;          // row-tile index
  bf16x8 A0 = __builtin_bit_cast(bf16x8, arow[tb * 64 + lane]);
  bf16x8 A1 = __builtin_bit_cast(bf16x8, arow[(tb + 1) * 64 + lane]);

  f32x16 z = {0.f,0.f,0.f,0.f,0.f,0.f,0.f,0.f,0.f,0.f,0.f,0.f,0.f,0.f,0.f,0.f};
  f32x16 rm0, rm1;
#pragma unroll
  for (int r = 0; r < 16; ++r) { rm0[r] = 1e30f; rm1[r] = 1e30f; }

  // candidate chunks: 4 x 1024 cands = 4 x 2048 uint4 (32 KB each)
  const uint4* __restrict__ cb = bcand + (batch * 256 + hf * 128) * 64;

  // async DMA of one chunk into buf: wave-uniform LDS base + lane*16 (m104)
  auto dma_chunk = [&](int ch, int buf) {
#pragma unroll
    for (int k = 0; k < 4; ++k) {
      const uint4* gsrc = cb + ch * 2048 + k * 512 + w * 64 + lane;
      uint4* ldst = &ldsFrag[buf][k * 512 + w * 64];   // wave-uniform
      __builtin_amdgcn_global_load_lds((ga_t*)gsrc, (la_t*)ldst, 16, 0, 0);
    }
  };

  dma_chunk(0, 0);
  __syncthreads();                       // drains DMA (vmcnt0) + publishes

  for (int ch = 0; ch < 4; ++ch) {
    const uint4* cur = ldsFrag[ch & 1];
    if (ch < 3) dma_chunk(ch + 1, (ch + 1) & 1);   // async under compute

#pragma unroll 2
    for (int i = 0; i < 16; ++i) {       // 32 tiles, 2 per iter
      bf16x8 B0 = __builtin_bit_cast(bf16x8, cur[(2 * i) * 64 + lane]);
      bf16x8 B1 = __builtin_bit_cast(bf16x8, cur[(2 * i + 1) * 64 + lane]);
      f32x16 acc0 = __builtin_amdgcn_mfma_f32_32x32x16_bf16(A0, B0, z, 0, 0, 0);
      f32x16 acc1 = __builtin_amdgcn_mfma_f32_32x32x16_bf16(A1, B0, z, 0, 0, 0);
      f32x16 acc2 = __builtin_amdgcn_mfma_f32_32x32x16_bf16(A0, B1, z, 0, 0, 0);
      f32x16 acc3 = __builtin_amdgcn_mfma_f32_32x32x16_bf16(A1, B1, z, 0, 0, 0);
#pragma unroll
      for (int r = 0; r < 16; ++r) {
        rm0[r] = fminf(fminf(rm0[r], acc0[r]), acc2[r]);   // v_min3_f32
        rm1[r] = fminf(fminf(rm1[r], acc1[r]), acc3[r]);   // v_min3_f32
      }
    }
    __syncthreads();                     // drains next DMA + guards buf reuse
  }

  // ---- epilogue: fold 32 cols per half (butterfly), store row-mins ----
#pragma unroll
  for (int msk = 1; msk <= 16; msk <<= 1)
#pragma unroll
    for (int r = 0; r < 16; ++r) {
      rm0[r] = fminf(rm0[r], __shfl_xor(rm0[r], msk, 64));
      rm1[r] = fminf(rm1[r], __shfl_xor(rm1[r], msk, 64));
    }

  float* gp = gpart + b * 512;           // this block's row-min slab
  if ((lane & 31) == 0) {                // lanes 0 and 32 (h = lane>>5)
    int h = lane >> 5;
#pragma unroll
    for (int r = 0; r < 16; ++r) {
      int rr = (r & 3) + 8 * (r >> 2) + 4 * h;
      gp[w * 64 + rr] = rm0[r];
      gp[w * 64 + 32 + rr] = rm1[r];
    }
  }
}

// ---- final: min the two candidate-halves, sum everything ----
__global__ __launch_bounds__(256) void chamfer_final_k(
    const float* __restrict__ gpart, float* __restrict__ out) {
  int i = blockIdx.x * 256 + threadIdx.x;   // 32768 threads x 4 rows
  float s = 0.0f;
#pragma unroll
  for (int e = 0; e < 4; ++e) {
    int rowid = 4 * i + e;               // 0 .. 131071
    int g = rowid >> 9, r = rowid & 511;
    s += fminf(gpart[(2 * g) * 512 + r], gpart[(2 * g + 1) * 512 + r]);
  }
  for (int off = 32; off > 0; off >>= 1) s += __shfl_down(s, off, 64);
  __shared__ float red[4];
  int lane = threadIdx.x & 63, wv = threadIdx.x >> 6;
  if (lane == 0) red[wv] = s;
  __syncthreads();
  if (threadIdx.x == 0) {
    float tt = (red[0] + red[1]) + (red[2] + red[3]);
    atomicAdd(out, tt * (1.0f / (float)PTS));
  }
}

extern "C" void kernel_launch(void* const* d_in, const int* in_sizes, int n_in,
                              void* d_out, int out_size, void* d_ws, size_t ws_size,
                              hipStream_t stream) {
  const float* x = (const float*)d_in[0];
  const float* y = (const float*)d_in[1];
  float* out = (float*)d_out;
  uint4* afX = (uint4*)d_ws;                 // 2048 tiles * 64 uint4 = 2 MB
  uint4* bfX = afX + 2048 * 64;              // 2 MB
  uint4* afY = bfX + 2048 * 64;              // 2 MB
  uint4* bfY = afY + 2048 * 64;              // 2 MB
  float* gpart = (float*)(bfY + 2048 * 64);  // 1 MB

  chamfer_pre_k<<<PTS / 256, 256, 0, stream>>>(x, y, afX, bfX, afY, bfY, out);
  chamfer_main_k<<<512, TPB, 0, stream>>>(afX, bfX, afY, bfY, gpart);
  chamfer_final_k<<<128, 256, 0, stream>>>(gpart, out);
}